// Round 1
// baseline (642.675 us; speedup 1.0000x reference)
//
#include <hip/hip_runtime.h>

#define DEV __device__ __forceinline__

typedef __attribute__((ext_vector_type(8))) short bf16x8;
typedef __attribute__((ext_vector_type(4))) float f32x4;

DEV float bf2f(unsigned short u) { return __uint_as_float(((unsigned int)u) << 16); }
DEV unsigned short f2bf(float f) {
    unsigned int x = __float_as_uint(f);
    return (unsigned short)((x + 0x7fffu + ((x >> 16) & 1u)) >> 16);
}
DEV float gelu_exact(float x) { return 0.5f * x * (1.0f + erff(x * 0.7071067811865475f)); }

DEV void gload16(const void* g, void* l) {
    __builtin_amdgcn_global_load_lds((const __attribute__((address_space(1))) void*)g,
                                     (__attribute__((address_space(3))) void*)l, 16, 0, 0);
}

// ---------------------------------------------------------------------------
// transpose + cast: w f32 [R][C] -> wT bf16 [C][R]
__global__ __launch_bounds__(256) void transpose_cast_w(const float* __restrict__ in,
                                                        unsigned short* __restrict__ out,
                                                        int R, int C) {
    __shared__ float tile[32][33];
    int c0 = blockIdx.x * 32, r0 = blockIdx.y * 32;
    int tx = threadIdx.x, ty = threadIdx.y;  // 32 x 8
#pragma unroll
    for (int i = 0; i < 32; i += 8)
        tile[ty + i][tx] = in[(size_t)(r0 + ty + i) * C + (c0 + tx)];
    __syncthreads();
#pragma unroll
    for (int i = 0; i < 32; i += 8)
        out[(size_t)(c0 + ty + i) * R + (r0 + tx)] = f2bf(tile[tx][ty + i]);
}

// transpose bf16 [R][C] -> [C][R], batched over z
__global__ __launch_bounds__(256) void transpose_bf16(const unsigned short* __restrict__ in,
                                                      unsigned short* __restrict__ out,
                                                      int R, int C, long sIn, long sOut) {
    in += (long)blockIdx.z * sIn;
    out += (long)blockIdx.z * sOut;
    __shared__ unsigned short tile[32][33];
    int c0 = blockIdx.x * 32, r0 = blockIdx.y * 32;
    int tx = threadIdx.x, ty = threadIdx.y;  // 32 x 8
#pragma unroll
    for (int i = 0; i < 32; i += 8)
        tile[ty + i][tx] = in[(size_t)(r0 + ty + i) * C + (c0 + tx)];
    __syncthreads();
#pragma unroll
    for (int i = 0; i < 32; i += 8)
        out[(size_t)(c0 + ty + i) * R + (r0 + tx)] = tile[tx][ty + i];
}

// f32 -> bf16 cast, 4 elems/thread
__global__ __launch_bounds__(256) void cast_f32_bf16(const float* __restrict__ in,
                                                     unsigned short* __restrict__ out, int n4) {
    int i = blockIdx.x * 256 + threadIdx.x;
    if (i >= n4) return;
    float4 v = ((const float4*)in)[i];
    unsigned short o[4] = {f2bf(v.x), f2bf(v.y), f2bf(v.z), f2bf(v.w)};
    *(uint2*)(out + (size_t)i * 4) = *(uint2*)o;
}

// ---------------------------------------------------------------------------
// bf16 MFMA GEMM, m97 structure: 128x128 tile, BK=32, 4 waves (2x2), 16 MFMA/K-step.
// C = act( scale * (A @ BT^T) + bias ), A:[M,K] bf16, BT:[N,K] bf16.
template <bool HAS_BIAS, bool GELU_ACT, bool OUT_F32, bool OUT_BF16>
__global__ __launch_bounds__(256) void gemm_bt(const unsigned short* __restrict__ A,
                                               const unsigned short* __restrict__ BT,
                                               const float* __restrict__ bias,
                                               float* __restrict__ Cf,
                                               unsigned short* __restrict__ Cb,
                                               int N, int K, float scale,
                                               long sA, long sB, long sC) {
    A += (long)blockIdx.z * sA;
    BT += (long)blockIdx.z * sB;

    const int tid = threadIdx.x;
    const int lane = tid & 63;
    const int wave = tid >> 6;
    const int wr = wave >> 1, wc = wave & 1;
    const int lhi = lane >> 4, llo = lane & 15;
    const int bm = blockIdx.x * 128, bn = blockIdx.y * 128;

    __shared__ unsigned short As[128 * 32];
    __shared__ unsigned short Bs[128 * 32];

    f32x4 acc[4][4] = {};

    // staging: chunk c in [0,512): row=c>>2, col=(c&3)*8; LDS elem off = c*8
    const int c0 = wave * 64 + lane;
    const int c1 = 256 + c0;
    const size_t a_off0 = (size_t)(bm + (c0 >> 2)) * K + ((c0 & 3) * 8);
    const size_t a_off1 = (size_t)(bm + (c1 >> 2)) * K + ((c1 & 3) * 8);
    const size_t b_off0 = (size_t)(bn + (c0 >> 2)) * K + ((c0 & 3) * 8);
    const size_t b_off1 = (size_t)(bn + (c1 >> 2)) * K + ((c1 & 3) * 8);
    unsigned short* asl0 = &As[(size_t)wave * 512];
    unsigned short* asl1 = &As[2048 + (size_t)wave * 512];
    unsigned short* bsl0 = &Bs[(size_t)wave * 512];
    unsigned short* bsl1 = &Bs[2048 + (size_t)wave * 512];

    for (int kt = 0; kt < K; kt += 32) {
        gload16(A + a_off0 + kt, asl0);
        gload16(A + a_off1 + kt, asl1);
        gload16(BT + b_off0 + kt, bsl0);
        gload16(BT + b_off1 + kt, bsl1);
        __syncthreads();

        bf16x8 a[4], b[4];
#pragma unroll
        for (int m = 0; m < 4; ++m)
            a[m] = *(const bf16x8*)&As[(wr * 64 + m * 16 + llo) * 32 + lhi * 8];
#pragma unroll
        for (int n = 0; n < 4; ++n)
            b[n] = *(const bf16x8*)&Bs[(wc * 64 + n * 16 + llo) * 32 + lhi * 8];
#pragma unroll
        for (int m = 0; m < 4; ++m)
#pragma unroll
            for (int n = 0; n < 4; ++n)
                acc[m][n] = __builtin_amdgcn_mfma_f32_16x16x32_bf16(a[m], b[n], acc[m][n], 0, 0, 0);
        __syncthreads();
    }

    // epilogue: C/D layout col=lane&15, row=(lane>>4)*4+j
#pragma unroll
    for (int m = 0; m < 4; ++m) {
#pragma unroll
        for (int n = 0; n < 4; ++n) {
            const int col = bn + wc * 64 + n * 16 + llo;
            float bcol = 0.f;
            if constexpr (HAS_BIAS) bcol = bias[col];
#pragma unroll
            for (int j = 0; j < 4; ++j) {
                const int row = bm + wr * 64 + m * 16 + lhi * 4 + j;
                float v = acc[m][n][j] * scale + bcol;
                if constexpr (GELU_ACT) v = gelu_exact(v);
                const size_t idx = (size_t)blockIdx.z * (size_t)sC + (size_t)row * N + col;
                if constexpr (OUT_F32) Cf[idx] = v;
                if constexpr (OUT_BF16) Cb[idx] = f2bf(v);
            }
        }
    }
}

// ---------------------------------------------------------------------------
// row softmax in place on bf16 scores, one block per row, T = 8*blockDim.x
__global__ __launch_bounds__(256) void softmax_rows(unsigned short* __restrict__ s, int T) {
    __shared__ float red[4];
    unsigned short* p = s + (size_t)blockIdx.x * T;
    const int tid = threadIdx.x;

    uint4 raw = *(const uint4*)(p + tid * 8);
    const unsigned short* u = (const unsigned short*)&raw;
    float v[8];
#pragma unroll
    for (int j = 0; j < 8; ++j) v[j] = bf2f(u[j]);

    float mx = -3.4e38f;
#pragma unroll
    for (int j = 0; j < 8; ++j) mx = fmaxf(mx, v[j]);
#pragma unroll
    for (int o = 32; o; o >>= 1) mx = fmaxf(mx, __shfl_xor(mx, o));
    if ((tid & 63) == 0) red[tid >> 6] = mx;
    __syncthreads();
    mx = fmaxf(fmaxf(red[0], red[1]), fmaxf(red[2], red[3]));
    __syncthreads();

    float sum = 0.f;
#pragma unroll
    for (int j = 0; j < 8; ++j) {
        v[j] = expf(v[j] - mx);
        sum += v[j];
    }
#pragma unroll
    for (int o = 32; o; o >>= 1) sum += __shfl_xor(sum, o);
    if ((tid & 63) == 0) red[tid >> 6] = sum;
    __syncthreads();
    sum = red[0] + red[1] + red[2] + red[3];
    const float inv = 1.0f / sum;

    unsigned short o8[8];
#pragma unroll
    for (int j = 0; j < 8; ++j) o8[j] = f2bf(v[j] * inv);
    *(uint4*)(p + tid * 8) = *(uint4*)o8;
}

// ---------------------------------------------------------------------------
// block reduce helper (256 threads = 4 waves)
DEV float block_sum(float v, float* red, int tid) {
#pragma unroll
    for (int o = 32; o; o >>= 1) v += __shfl_xor(v, o);
    if ((tid & 63) == 0) red[tid >> 6] = v;
    __syncthreads();
    v = red[0] + red[1] + red[2] + red[3];
    __syncthreads();
    return v;
}

// x1 = LN2( LN1(av + x)*g1+b1 + x ); writes x1 (f32) and bf16(x1). D=1024, 4/thread.
__global__ __launch_bounds__(256) void ln_double(const float* __restrict__ av,
                                                 const float* __restrict__ xin,
                                                 const float* __restrict__ g1, const float* __restrict__ b1,
                                                 const float* __restrict__ g2, const float* __restrict__ b2,
                                                 float* __restrict__ xout,
                                                 unsigned short* __restrict__ xbf, int D) {
    __shared__ float red[4];
    const int tid = threadIdx.x;
    const size_t base = (size_t)blockIdx.x * D + tid * 4;
    const float4 a4 = *(const float4*)(av + base);
    const float4 x4 = *(const float4*)(xin + base);
    float x[4] = {x4.x, x4.y, x4.z, x4.w};
    float t[4] = {a4.x + x[0], a4.y + x[1], a4.z + x[2], a4.w + x[3]};
    const float invD = 1.0f / D;

    float m = block_sum(t[0] + t[1] + t[2] + t[3], red, tid) * invD;
    float q = 0.f;
#pragma unroll
    for (int j = 0; j < 4; ++j) q += (t[j] - m) * (t[j] - m);
    q = block_sum(q, red, tid) * invD;
    float rs = rsqrtf(q + 1e-5f);

    float u[4];
#pragma unroll
    for (int j = 0; j < 4; ++j) {
        const int idx = tid * 4 + j;
        u[j] = (t[j] - m) * rs * g1[idx] + b1[idx] + x[j];
    }
    float m2 = block_sum(u[0] + u[1] + u[2] + u[3], red, tid) * invD;
    float q2 = 0.f;
#pragma unroll
    for (int j = 0; j < 4; ++j) q2 += (u[j] - m2) * (u[j] - m2);
    q2 = block_sum(q2, red, tid) * invD;
    float rs2 = rsqrtf(q2 + 1e-5f);

    float4 o4;
    unsigned short ob[4];
#pragma unroll
    for (int j = 0; j < 4; ++j) {
        const int idx = tid * 4 + j;
        float o = (u[j] - m2) * rs2 * g2[idx] + b2[idx];
        ((float*)&o4)[j] = o;
        ob[j] = f2bf(o);
    }
    *(float4*)(xout + base) = o4;
    *(uint2*)(xbf + base) = *(uint2*)ob;
}

// out = LN(a + b)*g + bb  (final LN to d_out)
__global__ __launch_bounds__(256) void ln_single(const float* __restrict__ a,
                                                 const float* __restrict__ b_,
                                                 const float* __restrict__ g, const float* __restrict__ bb,
                                                 float* __restrict__ out, int D) {
    __shared__ float red[4];
    const int tid = threadIdx.x;
    const size_t base = (size_t)blockIdx.x * D + tid * 4;
    const float4 a4 = *(const float4*)(a + base);
    const float4 x4 = *(const float4*)(b_ + base);
    float t[4] = {a4.x + x4.x, a4.y + x4.y, a4.z + x4.z, a4.w + x4.w};
    const float invD = 1.0f / D;
    float m = block_sum(t[0] + t[1] + t[2] + t[3], red, tid) * invD;
    float q = 0.f;
#pragma unroll
    for (int j = 0; j < 4; ++j) q += (t[j] - m) * (t[j] - m);
    q = block_sum(q, red, tid) * invD;
    float rs = rsqrtf(q + 1e-5f);
    float4 o4;
#pragma unroll
    for (int j = 0; j < 4; ++j) {
        const int idx = tid * 4 + j;
        ((float*)&o4)[j] = (t[j] - m) * rs * g[idx] + bb[idx];
    }
    *(float4*)(out + base) = o4;
}

// ---------------------------------------------------------------------------
extern "C" void kernel_launch(void* const* d_in, const int* in_sizes, int n_in,
                              void* d_out, int out_size, void* d_ws, size_t ws_size,
                              hipStream_t stream) {
    (void)in_sizes; (void)n_in; (void)out_size; (void)ws_size;
    constexpr int B = 4, S = 2048, T = 2048, D = 1024;
    constexpr int M = B * S;  // 8192
    constexpr long MD = (long)M * D;
    constexpr long ST = (long)S * T;

    const float* x = (const float*)d_in[0];
    const float* y = (const float*)d_in[1];
    const float* w_in[8] = {(const float*)d_in[2],  (const float*)d_in[4],  (const float*)d_in[6],
                            (const float*)d_in[10], (const float*)d_in[12], (const float*)d_in[14],
                            (const float*)d_in[18], (const float*)d_in[20]};
    const float* bq_m = (const float*)d_in[3];
    const float* bk_m = (const float*)d_in[5];
    const float* bv_m = (const float*)d_in[7];
    const float* g_m = (const float*)d_in[8];
    const float* b_m = (const float*)d_in[9];
    const float* bq_c = (const float*)d_in[11];
    const float* bk_c = (const float*)d_in[13];
    const float* bv_c = (const float*)d_in[15];
    const float* g_c = (const float*)d_in[16];
    const float* b_c = (const float*)d_in[17];
    const float* f0_b = (const float*)d_in[19];
    const float* f1_b = (const float*)d_in[21];
    const float* g_d = (const float*)d_in[22];
    const float* b_d = (const float*)d_in[23];
    float* dout = (float*)d_out;

    // workspace carve (~218 MB)
    char* p = (char*)d_ws;
    auto carve = [&](size_t bytes) { void* r = p; p += (bytes + 255) & ~(size_t)255; return r; };
    float* xcur = (float*)carve(MD * 4);                    // residual stream f32
    unsigned short* wT = (unsigned short*)carve((size_t)8 * D * D * 2);  // 8 transposed weights
    unsigned short* abf = (unsigned short*)carve(MD * 2);   // bf16 activations
    unsigned short* ybf = (unsigned short*)carve(MD * 2);
    unsigned short* Qb = (unsigned short*)carve(MD * 2);
    unsigned short* Kb = (unsigned short*)carve(MD * 2);
    unsigned short* Vb = (unsigned short*)carve(MD * 2);
    unsigned short* Vt = (unsigned short*)carve(MD * 2);
    unsigned short* scores = (unsigned short*)carve((size_t)B * ST * 2);
    float* tmp = (float*)carve(MD * 4);

    const dim3 blk256(256);
    const dim3 tb(32, 8);

    // --- setup: weight transposes + input casts
    for (int w = 0; w < 8; ++w)
        transpose_cast_w<<<dim3(32, 32), tb, 0, stream>>>(w_in[w], wT + (size_t)w * D * D, D, D);
    cast_f32_bf16<<<dim3(M * D / 4 / 256), blk256, 0, stream>>>(x, abf, M * D / 4);
    cast_f32_bf16<<<dim3(M * D / 4 / 256), blk256, 0, stream>>>(y, ybf, M * D / 4);

    const dim3 gProj(M / 128, D / 128, 1);        // 64 x 8
    const dim3 gScores(S / 128, T / 128, B);      // 16 x 16 x 4
    const dim3 gPV(S / 128, D / 128, B);          // 16 x 8 x 4
    unsigned short* wqm = wT + 0 * (size_t)D * D;
    unsigned short* wkm = wT + 1 * (size_t)D * D;
    unsigned short* wvm = wT + 2 * (size_t)D * D;
    unsigned short* wqc = wT + 3 * (size_t)D * D;
    unsigned short* wkc = wT + 4 * (size_t)D * D;
    unsigned short* wvc = wT + 5 * (size_t)D * D;
    unsigned short* wf0 = wT + 6 * (size_t)D * D;
    unsigned short* wf1 = wT + 7 * (size_t)D * D;

    // ===== stage 1: self attention =====
    gemm_bt<true, false, false, true><<<gProj, blk256, 0, stream>>>(abf, wqm, bq_m, nullptr, Qb, D, D, 1.f, 0, 0, 0);
    gemm_bt<true, false, false, true><<<gProj, blk256, 0, stream>>>(abf, wkm, bk_m, nullptr, Kb, D, D, 1.f, 0, 0, 0);
    gemm_bt<true, false, false, true><<<gProj, blk256, 0, stream>>>(abf, wvm, bv_m, nullptr, Vb, D, D, 1.f, 0, 0, 0);
    transpose_bf16<<<dim3(D / 32, T / 32, B), tb, 0, stream>>>(Vb, Vt, T, D, (long)T * D, (long)T * D);
    gemm_bt<false, false, false, true><<<gScores, blk256, 0, stream>>>(Qb, Kb, nullptr, nullptr, scores, T, D, 0.125f, (long)S * D, (long)T * D, ST);
    softmax_rows<<<dim3(B * S), blk256, 0, stream>>>(scores, T);
    gemm_bt<false, false, true, false><<<gPV, blk256, 0, stream>>>(scores, Vt, nullptr, tmp, nullptr, D, T, 1.f, ST, (long)T * D, (long)S * D);
    ln_double<<<dim3(M), blk256, 0, stream>>>(tmp, x, g_m, b_m, g_d, b_d, xcur, abf, D);

    // ===== stage 2: cross attention =====
    gemm_bt<true, false, false, true><<<gProj, blk256, 0, stream>>>(abf, wqc, bq_c, nullptr, Qb, D, D, 1.f, 0, 0, 0);
    gemm_bt<true, false, false, true><<<gProj, blk256, 0, stream>>>(ybf, wkc, bk_c, nullptr, Kb, D, D, 1.f, 0, 0, 0);
    gemm_bt<true, false, false, true><<<gProj, blk256, 0, stream>>>(ybf, wvc, bv_c, nullptr, Vb, D, D, 1.f, 0, 0, 0);
    transpose_bf16<<<dim3(D / 32, T / 32, B), tb, 0, stream>>>(Vb, Vt, T, D, (long)T * D, (long)T * D);
    gemm_bt<false, false, false, true><<<gScores, blk256, 0, stream>>>(Qb, Kb, nullptr, nullptr, scores, T, D, 0.125f, (long)S * D, (long)T * D, ST);
    softmax_rows<<<dim3(B * S), blk256, 0, stream>>>(scores, T);
    gemm_bt<false, false, true, false><<<gPV, blk256, 0, stream>>>(scores, Vt, nullptr, tmp, nullptr, D, T, 1.f, ST, (long)T * D, (long)S * D);
    ln_double<<<dim3(M), blk256, 0, stream>>>(tmp, xcur, g_c, b_c, g_d, b_d, xcur, abf, D);

    // ===== stage 3: FFN =====
    gemm_bt<true, true, false, true><<<gProj, blk256, 0, stream>>>(abf, wf0, f0_b, nullptr, Qb, D, D, 1.f, 0, 0, 0);
    gemm_bt<true, true, true, false><<<gProj, blk256, 0, stream>>>(Qb, wf1, f1_b, tmp, nullptr, D, D, 1.f, 0, 0, 0);
    ln_single<<<dim3(M), blk256, 0, stream>>>(tmp, xcur, g_d, b_d, dout, D);
}

// Round 2
// 613.245 us; speedup vs baseline: 1.0480x; 1.0480x over previous
//
#include <hip/hip_runtime.h>

#define DEV __device__ __forceinline__

typedef __attribute__((ext_vector_type(8))) short bf16x8;
typedef __attribute__((ext_vector_type(4))) float f32x4;

DEV float bf2f(unsigned short u) { return __uint_as_float(((unsigned int)u) << 16); }
DEV unsigned short f2bf(float f) {
    unsigned int x = __float_as_uint(f);
    return (unsigned short)((x + 0x7fffu + ((x >> 16) & 1u)) >> 16);
}
DEV float gelu_exact(float x) { return 0.5f * x * (1.0f + erff(x * 0.7071067811865475f)); }

DEV void gload16(const void* g, void* l) {
    __builtin_amdgcn_global_load_lds((const __attribute__((address_space(1))) void*)g,
                                     (__attribute__((address_space(3))) void*)l, 16, 0, 0);
}

// ---------------------------------------------------------------------------
// transpose + cast: w f32 [R][C] -> wT bf16 [C][R]
__global__ __launch_bounds__(256) void transpose_cast_w(const float* __restrict__ in,
                                                        unsigned short* __restrict__ out,
                                                        int R, int C) {
    __shared__ float tile[32][33];
    int c0 = blockIdx.x * 32, r0 = blockIdx.y * 32;
    int tx = threadIdx.x, ty = threadIdx.y;  // 32 x 8
#pragma unroll
    for (int i = 0; i < 32; i += 8)
        tile[ty + i][tx] = in[(size_t)(r0 + ty + i) * C + (c0 + tx)];
    __syncthreads();
#pragma unroll
    for (int i = 0; i < 32; i += 8)
        out[(size_t)(c0 + ty + i) * R + (r0 + tx)] = f2bf(tile[tx][ty + i]);
}

// transpose bf16 [R][C] -> [C][R], batched over z
__global__ __launch_bounds__(256) void transpose_bf16(const unsigned short* __restrict__ in,
                                                      unsigned short* __restrict__ out,
                                                      int R, int C, long sIn, long sOut) {
    in += (long)blockIdx.z * sIn;
    out += (long)blockIdx.z * sOut;
    __shared__ unsigned short tile[32][33];
    int c0 = blockIdx.x * 32, r0 = blockIdx.y * 32;
    int tx = threadIdx.x, ty = threadIdx.y;  // 32 x 8
#pragma unroll
    for (int i = 0; i < 32; i += 8)
        tile[ty + i][tx] = in[(size_t)(r0 + ty + i) * C + (c0 + tx)];
    __syncthreads();
#pragma unroll
    for (int i = 0; i < 32; i += 8)
        out[(size_t)(c0 + ty + i) * R + (r0 + tx)] = tile[tx][ty + i];
}

// f32 -> bf16 cast, 4 elems/thread
__global__ __launch_bounds__(256) void cast_f32_bf16(const float* __restrict__ in,
                                                     unsigned short* __restrict__ out, int n4) {
    int i = blockIdx.x * 256 + threadIdx.x;
    if (i >= n4) return;
    float4 v = ((const float4*)in)[i];
    unsigned short o[4] = {f2bf(v.x), f2bf(v.y), f2bf(v.z), f2bf(v.w)};
    *(uint2*)(out + (size_t)i * 4) = *(uint2*)o;
}

// ---------------------------------------------------------------------------
// 256x256 8-phase bf16 GEMM (T2+T3+T4+T5 port, plain HIP).
//   C = act( scale * (A @ BT^T) + bias ),  A:[M][K] lda, BT:[N][K] ldb, bf16.
//   8 waves (2M x 4N), BK=64, 2 K-tiles per iteration, 8 phases.
//   LDS: 2 bufs x {A0,A1,B0,B1} halves of [128][64] bf16, 128 KiB total.
//   Swizzle: 16B-chunk XOR  c' = (c & ~7) | ((c&7) ^ (row&7)) applied on BOTH
//   the global source of global_load_lds (LDS dest stays linear) and ds_read.

DEV bf16x8 ldfrag(const unsigned short* H, int row, int xk) {
    return *(const bf16x8*)(H + row * 64 + xk * 8);
}

template <int Q>
DEV void lda_quad(const unsigned short* Ah, int llo, int xk0, int xk1,
                  bf16x8& a00, bf16x8& a01, bf16x8& a10, bf16x8& a11) {
    a00 = ldfrag(Ah, (2 * Q) * 16 + llo, xk0);
    a01 = ldfrag(Ah, (2 * Q) * 16 + llo, xk1);
    a10 = ldfrag(Ah, (2 * Q + 1) * 16 + llo, xk0);
    a11 = ldfrag(Ah, (2 * Q + 1) * 16 + llo, xk1);
}

DEV void ldb_all(const unsigned short* Bh, int brow, int llo, int xk0, int xk1,
                 bf16x8 (&b)[4][2]) {
#pragma unroll
    for (int n = 0; n < 4; ++n) {
        b[n][0] = ldfrag(Bh, brow + n * 16 + llo, xk0);
        b[n][1] = ldfrag(Bh, brow + n * 16 + llo, xk1);
    }
}

template <int Q>
DEV void mfma16(const bf16x8& a00, const bf16x8& a01, const bf16x8& a10, const bf16x8& a11,
                const bf16x8 (&b)[4][2], f32x4 (&acc)[8][4]) {
#pragma unroll
    for (int n = 0; n < 4; ++n) {
        acc[2 * Q][n]     = __builtin_amdgcn_mfma_f32_16x16x32_bf16(a00, b[n][0], acc[2 * Q][n], 0, 0, 0);
        acc[2 * Q][n]     = __builtin_amdgcn_mfma_f32_16x16x32_bf16(a01, b[n][1], acc[2 * Q][n], 0, 0, 0);
        acc[2 * Q + 1][n] = __builtin_amdgcn_mfma_f32_16x16x32_bf16(a10, b[n][0], acc[2 * Q + 1][n], 0, 0, 0);
        acc[2 * Q + 1][n] = __builtin_amdgcn_mfma_f32_16x16x32_bf16(a11, b[n][1], acc[2 * Q + 1][n], 0, 0, 0);
    }
}

template <bool HAS_BIAS, bool GELU_ACT, bool OUT_F32>
__global__ __launch_bounds__(512, 2) void gemm256(const unsigned short* __restrict__ A,
                                                  const unsigned short* __restrict__ BT,
                                                  const float* __restrict__ bias,
                                                  float* __restrict__ Cf,
                                                  unsigned short* __restrict__ Cb,
                                                  int N, int K, int lda, int ldb, float scale,
                                                  long sA, long sB, long sC) {
    A += (long)blockIdx.z * sA;
    BT += (long)blockIdx.z * sB;

    const int tid = threadIdx.x;
    const int lane = tid & 63;
    const int wave = tid >> 6;          // 0..7
    const int wm = wave >> 2;           // 0..1 : A half / 128-row strip
    const int wn = wave & 3;            // 0..3 : 64-col strip
    const int llo = lane & 15, lhi = lane >> 4;
    const int bm = blockIdx.x * 256, bn = blockIdx.y * 256;
    const int brow = (wn & 1) * 64;

    __shared__ unsigned short lds[2][4][128 * 64];  // [buf][A0,A1,B0,B1] = 128 KiB

    // ds_read swizzled k-offsets (row&7 == llo&7 for all fragment rows)
    const int xk0 = (0 + lhi) ^ (llo & 7);
    const int xk1 = (4 + lhi) ^ (llo & 7);

    // staging: thread covers 16B chunks d0 = wave*64+lane and d1 = d0+512 of a
    // [128][64] half; source chunk column is XOR-swizzled so linear LDS ends up
    // holding the swizzled layout the ds_reads expect.
    const int d0 = wave * 64 + lane;
    const int sr0 = d0 >> 3, sq0 = (d0 & 7) ^ (sr0 & 7);
    const int d1 = 512 + d0;
    const int sr1 = d1 >> 3, sq1 = (d1 & 7) ^ (sr1 & 7);

    const unsigned short* gA0 = A + (size_t)bm * lda;
    const unsigned short* gA1 = A + (size_t)(bm + 128) * lda;
    const unsigned short* gB0 = BT + (size_t)bn * ldb;
    const unsigned short* gB1 = BT + (size_t)(bn + 128) * ldb;

#define STAGE(grow, ld, kt, l)                                              \
    {                                                                       \
        gload16((grow) + (size_t)sr0 * (ld) + (kt) + sq0 * 8, (l) + wave * 512);        \
        gload16((grow) + (size_t)sr1 * (ld) + (kt) + sq1 * 8, (l) + 4096 + wave * 512); \
    }

    f32x4 acc[8][4] = {};
    bf16x8 b[4][2];

#define PH(Q, BUF, LOADB, STG, TAIL)                                        \
    {                                                                       \
        bf16x8 a00, a01, a10, a11;                                          \
        lda_quad<Q>(lds[BUF][wm], llo, xk0, xk1, a00, a01, a10, a11);       \
        if (LOADB) ldb_all(lds[BUF][2 + (wn >> 1)], brow, llo, xk0, xk1, b);\
        STG;                                                                \
        __builtin_amdgcn_s_barrier();                                       \
        __builtin_amdgcn_s_setprio(1);                                      \
        mfma16<Q>(a00, a01, a10, a11, b, acc);                              \
        __builtin_amdgcn_s_setprio(0);                                      \
        TAIL;                                                               \
        __builtin_amdgcn_s_barrier();                                       \
        __builtin_amdgcn_sched_barrier(0);                                  \
    }

#define VM4 asm volatile("s_waitcnt vmcnt(4)" ::: "memory")
#define VM0 asm volatile("s_waitcnt vmcnt(0)" ::: "memory")
#define NOP ((void)0)

    const int nt = K >> 6;       // K-tiles of 64 (even, >= 4 for all our shapes)
    const int niter = nt >> 1;   // 2 K-tiles per iteration

    // prologue: buf0 <- tile0 (all 4 halves), buf1.B <- tile1 B halves
    STAGE(gA0, lda, 0, lds[0][0]);
    STAGE(gA1, lda, 0, lds[0][1]);
    STAGE(gB0, ldb, 0, lds[0][2]);
    STAGE(gB1, ldb, 0, lds[0][3]);
    STAGE(gB0, ldb, 64, lds[1][2]);
    STAGE(gB1, ldb, 64, lds[1][3]);
    VM4;                          // retire buf0's 4 halves; tile1 B stays in flight
    __builtin_amdgcn_s_barrier();

    int kt = 0;  // K offset of the buf0 tile this iteration
    for (int i = 0; i < niter - 1; ++i) {
        const int kt1 = kt + 64, kt2 = kt + 128, kt3 = kt + 192;
        // ---- K-tile in buf0 ----
        PH(0, 0, true,  STAGE(gA0, lda, kt1, lds[1][0]), NOP);  // stage A0(t+1)
        PH(1, 0, false, STAGE(gA1, lda, kt1, lds[1][1]), NOP);  // stage A1(t+1)
        PH(2, 0, false, STAGE(gB0, ldb, kt2, lds[0][2]), NOP);  // stage B0(t+2)
        PH(3, 0, false, STAGE(gB1, ldb, kt2, lds[0][3]), VM4);  // need A(t+1),B(t+1) landed
        // ---- K-tile in buf1 ----
        PH(0, 1, true,  STAGE(gA0, lda, kt2, lds[0][0]), NOP);  // stage A0(t+2)
        PH(1, 1, false, STAGE(gA1, lda, kt2, lds[0][1]), NOP);  // stage A1(t+2)
        PH(2, 1, false, STAGE(gB0, ldb, kt3, lds[1][2]), NOP);  // stage B0(t+3)
        PH(3, 1, false, STAGE(gB1, ldb, kt3, lds[1][3]), VM4);  // need A(t+2),B(t+2) landed
        kt += 128;
    }
    // peeled last iteration: tiles nt-2 (buf0), nt-1 (buf1); only A(nt-1) staged
    {
        const int kt1 = kt + 64;
        PH(0, 0, true,  STAGE(gA0, lda, kt1, lds[1][0]), NOP);
        PH(1, 0, false, STAGE(gA1, lda, kt1, lds[1][1]), NOP);
        PH(2, 0, false, NOP, NOP);
        PH(3, 0, false, NOP, VM0);  // drain: A(nt-1) + B(nt-1) must be in LDS
        PH(0, 1, true,  NOP, NOP);
        PH(1, 1, false, NOP, NOP);
        PH(2, 1, false, NOP, NOP);
        PH(3, 1, false, NOP, NOP);
    }
#undef PH
#undef STAGE
#undef VM4
#undef VM0
#undef NOP

    // epilogue: C/D frag layout col = llo, row = lhi*4 + j (verified R1)
#pragma unroll
    for (int m = 0; m < 8; ++m) {
#pragma unroll
        for (int n = 0; n < 4; ++n) {
            const int col = bn + wn * 64 + n * 16 + llo;
            float bcol = 0.f;
            if constexpr (HAS_BIAS) bcol = bias[col];
#pragma unroll
            for (int j = 0; j < 4; ++j) {
                const int row = bm + wm * 128 + m * 16 + lhi * 4 + j;
                float v = acc[m][n][j] * scale + bcol;
                if constexpr (GELU_ACT) v = gelu_exact(v);
                const size_t idx = (size_t)blockIdx.z * (size_t)sC + (size_t)row * N + col;
                if constexpr (OUT_F32) Cf[idx] = v;
                else Cb[idx] = f2bf(v);
            }
        }
    }
}

// ---------------------------------------------------------------------------
// row softmax in place on bf16 scores, one block per row, T = 8*blockDim.x
__global__ __launch_bounds__(256) void softmax_rows(unsigned short* __restrict__ s, int T) {
    __shared__ float red[4];
    unsigned short* p = s + (size_t)blockIdx.x * T;
    const int tid = threadIdx.x;

    uint4 raw = *(const uint4*)(p + tid * 8);
    const unsigned short* u = (const unsigned short*)&raw;
    float v[8];
#pragma unroll
    for (int j = 0; j < 8; ++j) v[j] = bf2f(u[j]);

    float mx = -3.4e38f;
#pragma unroll
    for (int j = 0; j < 8; ++j) mx = fmaxf(mx, v[j]);
#pragma unroll
    for (int o = 32; o; o >>= 1) mx = fmaxf(mx, __shfl_xor(mx, o));
    if ((tid & 63) == 0) red[tid >> 6] = mx;
    __syncthreads();
    mx = fmaxf(fmaxf(red[0], red[1]), fmaxf(red[2], red[3]));
    __syncthreads();

    float sum = 0.f;
#pragma unroll
    for (int j = 0; j < 8; ++j) {
        v[j] = expf(v[j] - mx);
        sum += v[j];
    }
#pragma unroll
    for (int o = 32; o; o >>= 1) sum += __shfl_xor(sum, o);
    if ((tid & 63) == 0) red[tid >> 6] = sum;
    __syncthreads();
    sum = red[0] + red[1] + red[2] + red[3];
    const float inv = 1.0f / sum;

    unsigned short o8[8];
#pragma unroll
    for (int j = 0; j < 8; ++j) o8[j] = f2bf(v[j] * inv);
    *(uint4*)(p + tid * 8) = *(uint4*)o8;
}

// ---------------------------------------------------------------------------
DEV float block_sum(float v, float* red, int tid) {
#pragma unroll
    for (int o = 32; o; o >>= 1) v += __shfl_xor(v, o);
    if ((tid & 63) == 0) red[tid >> 6] = v;
    __syncthreads();
    v = red[0] + red[1] + red[2] + red[3];
    __syncthreads();
    return v;
}

// x1 = LN2( LN1(av + x)*g1+b1 + x ); writes x1 (f32) and bf16(x1). D=1024, 4/thread.
__global__ __launch_bounds__(256) void ln_double(const float* __restrict__ av,
                                                 const float* __restrict__ xin,
                                                 const float* __restrict__ g1, const float* __restrict__ b1,
                                                 const float* __restrict__ g2, const float* __restrict__ b2,
                                                 float* __restrict__ xout,
                                                 unsigned short* __restrict__ xbf, int D) {
    __shared__ float red[4];
    const int tid = threadIdx.x;
    const size_t base = (size_t)blockIdx.x * D + tid * 4;
    const float4 a4 = *(const float4*)(av + base);
    const float4 x4 = *(const float4*)(xin + base);
    float x[4] = {x4.x, x4.y, x4.z, x4.w};
    float t[4] = {a4.x + x[0], a4.y + x[1], a4.z + x[2], a4.w + x[3]};
    const float invD = 1.0f / D;

    float m = block_sum(t[0] + t[1] + t[2] + t[3], red, tid) * invD;
    float q = 0.f;
#pragma unroll
    for (int j = 0; j < 4; ++j) q += (t[j] - m) * (t[j] - m);
    q = block_sum(q, red, tid) * invD;
    float rs = rsqrtf(q + 1e-5f);

    float u[4];
#pragma unroll
    for (int j = 0; j < 4; ++j) {
        const int idx = tid * 4 + j;
        u[j] = (t[j] - m) * rs * g1[idx] + b1[idx] + x[j];
    }
    float m2 = block_sum(u[0] + u[1] + u[2] + u[3], red, tid) * invD;
    float q2 = 0.f;
#pragma unroll
    for (int j = 0; j < 4; ++j) q2 += (u[j] - m2) * (u[j] - m2);
    q2 = block_sum(q2, red, tid) * invD;
    float rs2 = rsqrtf(q2 + 1e-5f);

    float4 o4;
    unsigned short ob[4];
#pragma unroll
    for (int j = 0; j < 4; ++j) {
        const int idx = tid * 4 + j;
        float o = (u[j] - m2) * rs2 * g2[idx] + b2[idx];
        ((float*)&o4)[j] = o;
        ob[j] = f2bf(o);
    }
    *(float4*)(xout + base) = o4;
    *(uint2*)(xbf + base) = *(uint2*)ob;
}

// out = LN(a + b)*g + bb  (final LN to d_out)
__global__ __launch_bounds__(256) void ln_single(const float* __restrict__ a,
                                                 const float* __restrict__ b_,
                                                 const float* __restrict__ g, const float* __restrict__ bb,
                                                 float* __restrict__ out, int D) {
    __shared__ float red[4];
    const int tid = threadIdx.x;
    const size_t base = (size_t)blockIdx.x * D + tid * 4;
    const float4 a4 = *(const float4*)(a + base);
    const float4 x4 = *(const float4*)(b_ + base);
    float t[4] = {a4.x + x4.x, a4.y + x4.y, a4.z + x4.z, a4.w + x4.w};
    const float invD = 1.0f / D;
    float m = block_sum(t[0] + t[1] + t[2] + t[3], red, tid) * invD;
    float q = 0.f;
#pragma unroll
    for (int j = 0; j < 4; ++j) q += (t[j] - m) * (t[j] - m);
    q = block_sum(q, red, tid) * invD;
    float rs = rsqrtf(q + 1e-5f);
    float4 o4;
#pragma unroll
    for (int j = 0; j < 4; ++j) {
        const int idx = tid * 4 + j;
        ((float*)&o4)[j] = (t[j] - m) * rs * g[idx] + bb[idx];
    }
    *(float4*)(out + base) = o4;
}

// ---------------------------------------------------------------------------
extern "C" void kernel_launch(void* const* d_in, const int* in_sizes, int n_in,
                              void* d_out, int out_size, void* d_ws, size_t ws_size,
                              hipStream_t stream) {
    (void)in_sizes; (void)n_in; (void)out_size; (void)ws_size;
    constexpr int B = 4, S = 2048, T = 2048, D = 1024;
    constexpr int M = B * S;  // 8192
    constexpr long MD = (long)M * D;
    constexpr long ST = (long)S * T;

    const float* x = (const float*)d_in[0];
    const float* y = (const float*)d_in[1];
    const float* w_in[8] = {(const float*)d_in[2],  (const float*)d_in[4],  (const float*)d_in[6],
                            (const float*)d_in[10], (const float*)d_in[12], (const float*)d_in[14],
                            (const float*)d_in[18], (const float*)d_in[20]};
    const float* bq_m = (const float*)d_in[3];
    const float* bk_m = (const float*)d_in[5];
    const float* bv_m = (const float*)d_in[7];
    const float* g_m = (const float*)d_in[8];
    const float* b_m = (const float*)d_in[9];
    const float* bq_c = (const float*)d_in[11];
    const float* bk_c = (const float*)d_in[13];
    const float* bv_c = (const float*)d_in[15];
    const float* g_c = (const float*)d_in[16];
    const float* b_c = (const float*)d_in[17];
    const float* f0_b = (const float*)d_in[19];
    const float* f1_b = (const float*)d_in[21];
    const float* g_d = (const float*)d_in[22];
    const float* b_d = (const float*)d_in[23];
    float* dout = (float*)d_out;

    // workspace carve (~218 MB)
    char* p = (char*)d_ws;
    auto carve = [&](size_t bytes) { void* r = p; p += (bytes + 255) & ~(size_t)255; return r; };
    float* xcur = (float*)carve(MD * 4);
    unsigned short* wT = (unsigned short*)carve((size_t)8 * D * D * 2);
    unsigned short* abf = (unsigned short*)carve(MD * 2);
    unsigned short* ybf = (unsigned short*)carve(MD * 2);
    unsigned short* Qb = (unsigned short*)carve(MD * 2);
    unsigned short* Kb = (unsigned short*)carve(MD * 2);
    unsigned short* Vb = (unsigned short*)carve(MD * 2);
    unsigned short* Vt = (unsigned short*)carve(MD * 2);
    unsigned short* scores = (unsigned short*)carve((size_t)B * ST * 2);
    float* tmp = (float*)carve(MD * 4);

    const dim3 blk256(256), blk512(512);
    const dim3 tb(32, 8);

    for (int w = 0; w < 8; ++w)
        transpose_cast_w<<<dim3(32, 32), tb, 0, stream>>>(w_in[w], wT + (size_t)w * D * D, D, D);
    cast_f32_bf16<<<dim3(M * D / 4 / 256), blk256, 0, stream>>>(x, abf, M * D / 4);
    cast_f32_bf16<<<dim3(M * D / 4 / 256), blk256, 0, stream>>>(y, ybf, M * D / 4);

    const dim3 gProj(M / 256, D / 256, 1);     // 32 x 4
    const dim3 gScores(S / 256, T / 256, B);   // 8 x 8 x 4
    const dim3 gPV(S / 256, D / 256, B);       // 8 x 4 x 4
    unsigned short* wqm = wT + 0 * (size_t)D * D;
    unsigned short* wkm = wT + 1 * (size_t)D * D;
    unsigned short* wvm = wT + 2 * (size_t)D * D;
    unsigned short* wqc = wT + 3 * (size_t)D * D;
    unsigned short* wkc = wT + 4 * (size_t)D * D;
    unsigned short* wvc = wT + 5 * (size_t)D * D;
    unsigned short* wf0 = wT + 6 * (size_t)D * D;
    unsigned short* wf1 = wT + 7 * (size_t)D * D;

    // ===== stage 1: self attention =====
    gemm256<true, false, false><<<gProj, blk512, 0, stream>>>(abf, wqm, bq_m, nullptr, Qb, D, D, D, D, 1.f, 0, 0, 0);
    gemm256<true, false, false><<<gProj, blk512, 0, stream>>>(abf, wkm, bk_m, nullptr, Kb, D, D, D, D, 1.f, 0, 0, 0);
    gemm256<true, false, false><<<gProj, blk512, 0, stream>>>(abf, wvm, bv_m, nullptr, Vb, D, D, D, D, 1.f, 0, 0, 0);
    transpose_bf16<<<dim3(D / 32, T / 32, B), tb, 0, stream>>>(Vb, Vt, T, D, (long)T * D, (long)T * D);
    gemm256<false, false, false><<<gScores, blk512, 0, stream>>>(Qb, Kb, nullptr, nullptr, scores, T, D, D, D, 0.125f, (long)S * D, (long)T * D, ST);
    softmax_rows<<<dim3(B * S), blk256, 0, stream>>>(scores, T);
    gemm256<false, false, true><<<gPV, blk512, 0, stream>>>(scores, Vt, nullptr, tmp, nullptr, D, T, T, T, 1.f, ST, (long)T * D, (long)S * D);
    ln_double<<<dim3(M), blk256, 0, stream>>>(tmp, x, g_m, b_m, g_d, b_d, xcur, abf, D);

    // ===== stage 2: cross attention =====
    gemm256<true, false, false><<<gProj, blk512, 0, stream>>>(abf, wqc, bq_c, nullptr, Qb, D, D, D, D, 1.f, 0, 0, 0);
    gemm256<true, false, false><<<gProj, blk512, 0, stream>>>(ybf, wkc, bk_c, nullptr, Kb, D, D, D, D, 1.f, 0, 0, 0);
    gemm256<true, false, false><<<gProj, blk512, 0, stream>>>(ybf, wvc, bv_c, nullptr, Vb, D, D, D, D, 1.f, 0, 0, 0);
    transpose_bf16<<<dim3(D / 32, T / 32, B), tb, 0, stream>>>(Vb, Vt, T, D, (long)T * D, (long)T * D);
    gemm256<false, false, false><<<gScores, blk512, 0, stream>>>(Qb, Kb, nullptr, nullptr, scores, T, D, D, D, 0.125f, (long)S * D, (long)T * D, ST);
    softmax_rows<<<dim3(B * S), blk256, 0, stream>>>(scores, T);
    gemm256<false, false, true><<<gPV, blk512, 0, stream>>>(scores, Vt, nullptr, tmp, nullptr, D, T, T, T, 1.f, ST, (long)T * D, (long)S * D);
    ln_double<<<dim3(M), blk256, 0, stream>>>(tmp, xcur, g_c, b_c, g_d, b_d, xcur, abf, D);

    // ===== stage 3: FFN =====
    gemm256<true, true, false><<<gProj, blk512, 0, stream>>>(abf, wf0, f0_b, nullptr, Qb, D, D, D, D, 1.f, 0, 0, 0);
    gemm256<true, true, true><<<gProj, blk512, 0, stream>>>(Qb, wf1, f1_b, tmp, nullptr, D, D, D, D, 1.f, 0, 0, 0);
    ln_single<<<dim3(M), blk256, 0, stream>>>(tmp, xcur, g_d, b_d, dout, D);
}

// Round 3
// 552.356 us; speedup vs baseline: 1.1635x; 1.1102x over previous
//
#include <hip/hip_runtime.h>

#define DEV __device__ __forceinline__

typedef __attribute__((ext_vector_type(8))) short bf16x8;
typedef __attribute__((ext_vector_type(4))) float f32x4;

DEV float bf2f(unsigned short u) { return __uint_as_float(((unsigned int)u) << 16); }
DEV unsigned short f2bf(float f) {
    unsigned int x = __float_as_uint(f);
    return (unsigned short)((x + 0x7fffu + ((x >> 16) & 1u)) >> 16);
}
DEV float gelu_exact(float x) { return 0.5f * x * (1.0f + erff(x * 0.7071067811865475f)); }

DEV void gload16(const void* g, void* l) {
    __builtin_amdgcn_global_load_lds((const __attribute__((address_space(1))) void*)g,
                                     (__attribute__((address_space(3))) void*)l, 16, 0, 0);
}

// ---------------------------------------------------------------------------
// transpose + cast: w f32 [R][C] -> wT bf16 [C][R]
__global__ __launch_bounds__(256) void transpose_cast_w(const float* __restrict__ in,
                                                        unsigned short* __restrict__ out,
                                                        int R, int C) {
    __shared__ float tile[32][33];
    int c0 = blockIdx.x * 32, r0 = blockIdx.y * 32;
    int tx = threadIdx.x, ty = threadIdx.y;  // 32 x 8
#pragma unroll
    for (int i = 0; i < 32; i += 8)
        tile[ty + i][tx] = in[(size_t)(r0 + ty + i) * C + (c0 + tx)];
    __syncthreads();
#pragma unroll
    for (int i = 0; i < 32; i += 8)
        out[(size_t)(c0 + ty + i) * R + (r0 + tx)] = f2bf(tile[tx][ty + i]);
}

// f32 -> bf16 cast, 4 elems/thread
__global__ __launch_bounds__(256) void cast_f32_bf16(const float* __restrict__ in,
                                                     unsigned short* __restrict__ out, int n4) {
    int i = blockIdx.x * 256 + threadIdx.x;
    if (i >= n4) return;
    float4 v = ((const float4*)in)[i];
    unsigned short o[4] = {f2bf(v.x), f2bf(v.y), f2bf(v.z), f2bf(v.w)};
    *(uint2*)(out + (size_t)i * 4) = *(uint2*)o;
}

// ---------------------------------------------------------------------------
// 256x256 8-phase bf16 GEMM (T2+T3+T4+T5).
//   C = act( scale * (A @ BT^T) + bias ),  A:[M][K] lda, BT:[N][K] ldb, bf16.
//   8 waves (2M x 4N), BK=64, 2 K-tiles per iteration, 8 phases.
//   LDS: 2 bufs x {A0,A1,B0,B1} halves of [128][64] bf16, 128 KiB total.
//   Swizzle: 16B-chunk XOR  c' = (c & ~7) | ((c&7) ^ (row&7)) applied on BOTH
//   the global source of global_load_lds (LDS dest linear) and the ds_read.
//   BIAS_MODE: 0 = none, 1 = per-column, 2 = per-row.

DEV bf16x8 ldfrag(const unsigned short* H, int row, int xk) {
    return *(const bf16x8*)(H + row * 64 + xk * 8);
}

template <int Q>
DEV void lda_quad(const unsigned short* Ah, int llo, int xk0, int xk1, bf16x8 (&a)[2][2]) {
    a[0][0] = ldfrag(Ah, (2 * Q) * 16 + llo, xk0);
    a[0][1] = ldfrag(Ah, (2 * Q) * 16 + llo, xk1);
    a[1][0] = ldfrag(Ah, (2 * Q + 1) * 16 + llo, xk0);
    a[1][1] = ldfrag(Ah, (2 * Q + 1) * 16 + llo, xk1);
}

DEV void ldb_all(const unsigned short* Bh, int brow, int llo, int xk0, int xk1,
                 bf16x8 (&b)[4][2]) {
#pragma unroll
    for (int n = 0; n < 4; ++n) {
        b[n][0] = ldfrag(Bh, brow + n * 16 + llo, xk0);
        b[n][1] = ldfrag(Bh, brow + n * 16 + llo, xk1);
    }
}

// k-slot-outer order: 8 independent accumulators between reuses (hide MFMA latency)
template <int Q>
DEV void mfma16(const bf16x8 (&a)[2][2], const bf16x8 (&b)[4][2], f32x4 (&acc)[8][4]) {
#pragma unroll
    for (int ks = 0; ks < 2; ++ks)
#pragma unroll
        for (int n = 0; n < 4; ++n) {
            acc[2 * Q][n]     = __builtin_amdgcn_mfma_f32_16x16x32_bf16(a[0][ks], b[n][ks], acc[2 * Q][n], 0, 0, 0);
            acc[2 * Q + 1][n] = __builtin_amdgcn_mfma_f32_16x16x32_bf16(a[1][ks], b[n][ks], acc[2 * Q + 1][n], 0, 0, 0);
        }
}

template <int BIAS_MODE, bool GELU_ACT, bool OUT_F32>
__global__ __launch_bounds__(512, 2) void gemm256(const unsigned short* __restrict__ A,
                                                  const unsigned short* __restrict__ BT,
                                                  const float* __restrict__ bias,
                                                  float* __restrict__ Cf,
                                                  unsigned short* __restrict__ Cb,
                                                  int N, int K, int lda, int ldb, float scale,
                                                  long sA, long sB, long sC, long sBias) {
    A += (long)blockIdx.z * sA;
    BT += (long)blockIdx.z * sB;
    if (BIAS_MODE) bias += (long)blockIdx.z * sBias;

    const int tid = threadIdx.x;
    const int lane = tid & 63;
    const int wave = tid >> 6;          // 0..7
    const int wm = wave >> 2;           // 0..1 : 128-row strip
    const int wn = wave & 3;            // 0..3 : 64-col strip
    const int llo = lane & 15, lhi = lane >> 4;
    const int bm = blockIdx.x * 256, bn = blockIdx.y * 256;
    const int brow = (wn & 1) * 64;

    __shared__ unsigned short lds[2][4][128 * 64];  // [buf][A0,A1,B0,B1] = 128 KiB

    // ds_read swizzled k-offsets
    const int xk0 = (0 + lhi) ^ (llo & 7);
    const int xk1 = (4 + lhi) ^ (llo & 7);

    // staging: thread covers 16B chunks d0 = wave*64+lane and d1 = d0+512 of a
    // [128][64] half; source chunk column XOR-swizzled, LDS dest linear.
    const int d0 = wave * 64 + lane;
    const int sr0 = d0 >> 3, sq0 = (d0 & 7) ^ (sr0 & 7);
    const int d1 = 512 + d0;
    const int sr1 = d1 >> 3, sq1 = (d1 & 7) ^ (sr1 & 7);

    const unsigned short* gA0 = A + (size_t)bm * lda;
    const unsigned short* gA1 = A + (size_t)(bm + 128) * lda;
    const unsigned short* gB0 = BT + (size_t)bn * ldb;
    const unsigned short* gB1 = BT + (size_t)(bn + 128) * ldb;

#define STAGE(grow, ld, kt, l)                                                          \
    {                                                                                   \
        gload16((grow) + (size_t)sr0 * (ld) + (kt) + sq0 * 8, (l) + wave * 512);        \
        gload16((grow) + (size_t)sr1 * (ld) + (kt) + sq1 * 8, (l) + 4096 + wave * 512); \
    }

    f32x4 acc[8][4] = {};
    bf16x8 b[4][2];

#define PH(Q, BUF, LOADB, STG, TAIL)                                        \
    {                                                                       \
        bf16x8 afr[2][2];                                                   \
        lda_quad<Q>(lds[BUF][wm], llo, xk0, xk1, afr);                      \
        if (LOADB) ldb_all(lds[BUF][2 + (wn >> 1)], brow, llo, xk0, xk1, b);\
        STG;                                                                \
        __builtin_amdgcn_s_barrier();                                       \
        __builtin_amdgcn_s_setprio(1);                                      \
        mfma16<Q>(afr, b, acc);                                             \
        __builtin_amdgcn_s_setprio(0);                                      \
        TAIL;                                                               \
        __builtin_amdgcn_s_barrier();                                       \
    }

#define VM4 asm volatile("s_waitcnt vmcnt(4)" ::: "memory")
#define VM0 asm volatile("s_waitcnt vmcnt(0)" ::: "memory")
#define NOP ((void)0)

    const int nt = K >> 6;       // K-tiles of 64
    const int niter = nt >> 1;   // 2 K-tiles per iteration

    // prologue: buf0 <- tile0 (4 halves), buf1.B <- tile1 B halves
    STAGE(gA0, lda, 0, lds[0][0]);
    STAGE(gA1, lda, 0, lds[0][1]);
    STAGE(gB0, ldb, 0, lds[0][2]);
    STAGE(gB1, ldb, 0, lds[0][3]);
    STAGE(gB0, ldb, 64, lds[1][2]);
    STAGE(gB1, ldb, 64, lds[1][3]);
    VM4;
    __builtin_amdgcn_s_barrier();

    int kt = 0;
    for (int i = 0; i < niter - 1; ++i) {
        const int kt1 = kt + 64, kt2 = kt + 128, kt3 = kt + 192;
        PH(0, 0, true,  STAGE(gA0, lda, kt1, lds[1][0]), NOP);
        PH(1, 0, false, STAGE(gA1, lda, kt1, lds[1][1]), NOP);
        PH(2, 0, false, STAGE(gB0, ldb, kt2, lds[0][2]), NOP);
        PH(3, 0, false, STAGE(gB1, ldb, kt2, lds[0][3]), VM4);
        PH(0, 1, true,  STAGE(gA0, lda, kt2, lds[0][0]), NOP);
        PH(1, 1, false, STAGE(gA1, lda, kt2, lds[0][1]), NOP);
        PH(2, 1, false, STAGE(gB0, ldb, kt3, lds[1][2]), NOP);
        PH(3, 1, false, STAGE(gB1, ldb, kt3, lds[1][3]), VM4);
        kt += 128;
    }
    {
        const int kt1 = kt + 64;
        PH(0, 0, true,  STAGE(gA0, lda, kt1, lds[1][0]), NOP);
        PH(1, 0, false, STAGE(gA1, lda, kt1, lds[1][1]), NOP);
        PH(2, 0, false, NOP, NOP);
        PH(3, 0, false, NOP, VM0);
        PH(0, 1, true,  NOP, NOP);
        PH(1, 1, false, NOP, NOP);
        PH(2, 1, false, NOP, NOP);
        PH(3, 1, false, NOP, NOP);
    }
#undef PH
#undef STAGE
#undef VM4
#undef VM0
#undef NOP

    // epilogue: C/D frag layout col = llo, row = lhi*4 + j
#pragma unroll
    for (int m = 0; m < 8; ++m) {
#pragma unroll
        for (int n = 0; n < 4; ++n) {
            const int col = bn + wn * 64 + n * 16 + llo;
            float bcol = 0.f;
            if constexpr (BIAS_MODE == 1) bcol = bias[col];
#pragma unroll
            for (int j = 0; j < 4; ++j) {
                const int row = bm + wm * 128 + m * 16 + lhi * 4 + j;
                float v = acc[m][n][j] * scale + bcol;
                if constexpr (BIAS_MODE == 2) v += bias[row];
                if constexpr (GELU_ACT) v = gelu_exact(v);
                const size_t idx = (size_t)blockIdx.z * (size_t)sC + (size_t)row * N + col;
                if constexpr (OUT_F32) Cf[idx] = v;
                else Cb[idx] = f2bf(v);
            }
        }
    }
}

// ---------------------------------------------------------------------------
// row softmax in place on bf16 scores, one block per row, T = 8*blockDim.x
__global__ __launch_bounds__(256) void softmax_rows(unsigned short* __restrict__ s, int T) {
    __shared__ float red[4];
    unsigned short* p = s + (size_t)blockIdx.x * T;
    const int tid = threadIdx.x;

    uint4 raw = *(const uint4*)(p + tid * 8);
    const unsigned short* u = (const unsigned short*)&raw;
    float v[8];
#pragma unroll
    for (int j = 0; j < 8; ++j) v[j] = bf2f(u[j]);

    float mx = -3.4e38f;
#pragma unroll
    for (int j = 0; j < 8; ++j) mx = fmaxf(mx, v[j]);
#pragma unroll
    for (int o = 32; o; o >>= 1) mx = fmaxf(mx, __shfl_xor(mx, o));
    if ((tid & 63) == 0) red[tid >> 6] = mx;
    __syncthreads();
    mx = fmaxf(fmaxf(red[0], red[1]), fmaxf(red[2], red[3]));
    __syncthreads();

    float sum = 0.f;
#pragma unroll
    for (int j = 0; j < 8; ++j) {
        v[j] = expf(v[j] - mx);
        sum += v[j];
    }
#pragma unroll
    for (int o = 32; o; o >>= 1) sum += __shfl_xor(sum, o);
    if ((tid & 63) == 0) red[tid >> 6] = sum;
    __syncthreads();
    sum = red[0] + red[1] + red[2] + red[3];
    const float inv = 1.0f / sum;

    unsigned short o8[8];
#pragma unroll
    for (int j = 0; j < 8; ++j) o8[j] = f2bf(v[j] * inv);
    *(uint4*)(p + tid * 8) = *(uint4*)o8;
}

// ---------------------------------------------------------------------------
DEV float block_sum(float v, float* red, int tid) {
#pragma unroll
    for (int o = 32; o; o >>= 1) v += __shfl_xor(v, o);
    if ((tid & 63) == 0) red[tid >> 6] = v;
    __syncthreads();
    v = red[0] + red[1] + red[2] + red[3];
    __syncthreads();
    return v;
}

// x1 = LN2( LN1(av + x)*g1+b1 + x ); writes x1 (f32) and bf16(x1). D=1024, 4/thread.
__global__ __launch_bounds__(256) void ln_double(const float* __restrict__ av,
                                                 const float* __restrict__ xin,
                                                 const float* __restrict__ g1, const float* __restrict__ b1,
                                                 const float* __restrict__ g2, const float* __restrict__ b2,
                                                 float* __restrict__ xout,
                                                 unsigned short* __restrict__ xbf, int D) {
    __shared__ float red[4];
    const int tid = threadIdx.x;
    const size_t base = (size_t)blockIdx.x * D + tid * 4;
    const float4 a4 = *(const float4*)(av + base);
    const float4 x4 = *(const float4*)(xin + base);
    float x[4] = {x4.x, x4.y, x4.z, x4.w};
    float t[4] = {a4.x + x[0], a4.y + x[1], a4.z + x[2], a4.w + x[3]};
    const float invD = 1.0f / D;

    float m = block_sum(t[0] + t[1] + t[2] + t[3], red, tid) * invD;
    float q = 0.f;
#pragma unroll
    for (int j = 0; j < 4; ++j) q += (t[j] - m) * (t[j] - m);
    q = block_sum(q, red, tid) * invD;
    float rs = rsqrtf(q + 1e-5f);

    float u[4];
#pragma unroll
    for (int j = 0; j < 4; ++j) {
        const int idx = tid * 4 + j;
        u[j] = (t[j] - m) * rs * g1[idx] + b1[idx] + x[j];
    }
    float m2 = block_sum(u[0] + u[1] + u[2] + u[3], red, tid) * invD;
    float q2 = 0.f;
#pragma unroll
    for (int j = 0; j < 4; ++j) q2 += (u[j] - m2) * (u[j] - m2);
    q2 = block_sum(q2, red, tid) * invD;
    float rs2 = rsqrtf(q2 + 1e-5f);

    float4 o4;
    unsigned short ob[4];
#pragma unroll
    for (int j = 0; j < 4; ++j) {
        const int idx = tid * 4 + j;
        float o = (u[j] - m2) * rs2 * g2[idx] + b2[idx];
        ((float*)&o4)[j] = o;
        ob[j] = f2bf(o);
    }
    *(float4*)(xout + base) = o4;
    *(uint2*)(xbf + base) = *(uint2*)ob;
}

// out = LN(a + b)*g + bb  (final LN to d_out)
__global__ __launch_bounds__(256) void ln_single(const float* __restrict__ a,
                                                 const float* __restrict__ b_,
                                                 const float* __restrict__ g, const float* __restrict__ bb,
                                                 float* __restrict__ out, int D) {
    __shared__ float red[4];
    const int tid = threadIdx.x;
    const size_t base = (size_t)blockIdx.x * D + tid * 4;
    const float4 a4 = *(const float4*)(a + base);
    const float4 x4 = *(const float4*)(b_ + base);
    float t[4] = {a4.x + x4.x, a4.y + x4.y, a4.z + x4.z, a4.w + x4.w};
    const float invD = 1.0f / D;
    float m = block_sum(t[0] + t[1] + t[2] + t[3], red, tid) * invD;
    float q = 0.f;
#pragma unroll
    for (int j = 0; j < 4; ++j) q += (t[j] - m) * (t[j] - m);
    q = block_sum(q, red, tid) * invD;
    float rs = rsqrtf(q + 1e-5f);
    float4 o4;
#pragma unroll
    for (int j = 0; j < 4; ++j) {
        const int idx = tid * 4 + j;
        ((float*)&o4)[j] = (t[j] - m) * rs * g[idx] + bb[idx];
    }
    *(float4*)(out + base) = o4;
}

// ---------------------------------------------------------------------------
extern "C" void kernel_launch(void* const* d_in, const int* in_sizes, int n_in,
                              void* d_out, int out_size, void* d_ws, size_t ws_size,
                              hipStream_t stream) {
    (void)in_sizes; (void)n_in; (void)out_size; (void)ws_size;
    constexpr int B = 4, S = 2048, T = 2048, D = 1024;
    constexpr int M = B * S;  // 8192
    constexpr long MD = (long)M * D;
    constexpr long ST = (long)S * T;
    constexpr long DD = (long)D * D;

    const float* x = (const float*)d_in[0];
    const float* y = (const float*)d_in[1];
    const float* w_in[8] = {(const float*)d_in[2],  (const float*)d_in[4],  (const float*)d_in[6],
                            (const float*)d_in[10], (const float*)d_in[12], (const float*)d_in[14],
                            (const float*)d_in[18], (const float*)d_in[20]};
    const float* bq_m = (const float*)d_in[3];
    const float* bk_m = (const float*)d_in[5];
    const float* bv_m = (const float*)d_in[7];
    const float* g_m = (const float*)d_in[8];
    const float* b_m = (const float*)d_in[9];
    const float* bq_c = (const float*)d_in[11];
    const float* bk_c = (const float*)d_in[13];
    const float* bv_c = (const float*)d_in[15];
    const float* g_c = (const float*)d_in[16];
    const float* b_c = (const float*)d_in[17];
    const float* f0_b = (const float*)d_in[19];
    const float* f1_b = (const float*)d_in[21];
    const float* g_d = (const float*)d_in[22];
    const float* b_d = (const float*)d_in[23];
    float* dout = (float*)d_out;

    // workspace carve
    char* p = (char*)d_ws;
    auto carve = [&](size_t bytes) { void* r = p; p += (bytes + 255) & ~(size_t)255; return r; };
    float* xcur = (float*)carve(MD * 4);
    unsigned short* wT = (unsigned short*)carve((size_t)8 * DD * 2);
    unsigned short* abf = (unsigned short*)carve(MD * 2);   // abf, ybf adjacent (stride MD)
    unsigned short* ybf = (unsigned short*)carve(MD * 2);
    unsigned short* Qb = (unsigned short*)carve(MD * 2);    // Qb, Kb adjacent (stride MD)
    unsigned short* Kb = (unsigned short*)carve(MD * 2);
    unsigned short* Vt = (unsigned short*)carve(MD * 2);
    unsigned short* scores = (unsigned short*)carve((size_t)B * ST * 2);
    float* tmp = (float*)carve(MD * 4);
    float* bqk_m = (float*)carve(2 * D * 4);  // [bq_m ; bk_m]
    float* bqk_c = (float*)carve(2 * D * 4);  // [bq_c ; bk_c]

    const dim3 blk256(256), blk512(512);
    const dim3 tb(32, 8);

    // setup: weight transposes, input casts, adjacent bias staging
    for (int w = 0; w < 8; ++w)
        transpose_cast_w<<<dim3(32, 32), tb, 0, stream>>>(w_in[w], wT + (size_t)w * DD, D, D);
    cast_f32_bf16<<<dim3(M * D / 4 / 256), blk256, 0, stream>>>(x, abf, M * D / 4);
    cast_f32_bf16<<<dim3(M * D / 4 / 256), blk256, 0, stream>>>(y, ybf, M * D / 4);
    hipMemcpyAsync(bqk_m, bq_m, D * 4, hipMemcpyDeviceToDevice, stream);
    hipMemcpyAsync(bqk_m + D, bk_m, D * 4, hipMemcpyDeviceToDevice, stream);
    hipMemcpyAsync(bqk_c, bq_c, D * 4, hipMemcpyDeviceToDevice, stream);
    hipMemcpyAsync(bqk_c + D, bk_c, D * 4, hipMemcpyDeviceToDevice, stream);

    unsigned short* wqm = wT + 0 * DD;
    unsigned short* wvm = wT + 2 * DD;
    unsigned short* wqc = wT + 3 * DD;
    unsigned short* wvc = wT + 5 * DD;
    unsigned short* wf0 = wT + 6 * DD;
    unsigned short* wf1 = wT + 7 * DD;

    const dim3 gQK(M / 256, D / 256, 2);     // 32 x 4 x 2 = 256 blocks
    const dim3 gVt(D / 256, T / 256, B);     // 4 x 8 x 4  = 128 blocks
    const dim3 gScores(S / 256, T / 256, B); // 8 x 8 x 4  = 256 blocks
    const dim3 gPV(S / 256, D / 256, B);     // 8 x 4 x 4  = 128 blocks
    const dim3 gFFN(M / 256, D / 256, 1);    // 32 x 4     = 128 blocks

    // ===== stage 1: self attention =====
    // fused Q/K projection: z selects weight (stride DD), output (stride MD), bias (stride D); A shared
    gemm256<1, false, false><<<gQK, blk512, 0, stream>>>(abf, wqm, bqk_m, nullptr, Qb, D, D, D, D, 1.f, 0, DD, MD, D);
    // Vt[d][t] = sum_k wvT[d][k]*kv[t][k] + bv[d]  (direct transposed V)
    gemm256<2, false, false><<<gVt, blk512, 0, stream>>>(wvm, abf, bv_m, nullptr, Vt, T, D, D, D, 1.f, 0, (long)S * D, (long)D * T, 0);
    gemm256<0, false, false><<<gScores, blk512, 0, stream>>>(Qb, Kb, nullptr, nullptr, scores, T, D, D, D, 0.125f, (long)S * D, (long)T * D, ST, 0);
    softmax_rows<<<dim3(B * S), blk256, 0, stream>>>(scores, T);
    gemm256<0, false, true><<<gPV, blk512, 0, stream>>>(scores, Vt, nullptr, tmp, nullptr, D, T, T, T, 1.f, ST, (long)T * D, (long)S * D, 0);
    ln_double<<<dim3(M), blk256, 0, stream>>>(tmp, x, g_m, b_m, g_d, b_d, xcur, abf, D);

    // ===== stage 2: cross attention =====
    // Q from abf (z=0), K from ybf (z=1): sA = MD since ybf = abf + MD
    gemm256<1, false, false><<<gQK, blk512, 0, stream>>>(abf, wqc, bqk_c, nullptr, Qb, D, D, D, D, 1.f, MD, DD, MD, D);
    gemm256<2, false, false><<<gVt, blk512, 0, stream>>>(wvc, ybf, bv_c, nullptr, Vt, T, D, D, D, 1.f, 0, (long)S * D, (long)D * T, 0);
    gemm256<0, false, false><<<gScores, blk512, 0, stream>>>(Qb, Kb, nullptr, nullptr, scores, T, D, D, D, 0.125f, (long)S * D, (long)T * D, ST, 0);
    softmax_rows<<<dim3(B * S), blk256, 0, stream>>>(scores, T);
    gemm256<0, false, true><<<gPV, blk512, 0, stream>>>(scores, Vt, nullptr, tmp, nullptr, D, T, T, T, 1.f, ST, (long)T * D, (long)S * D, 0);
    ln_double<<<dim3(M), blk256, 0, stream>>>(tmp, xcur, g_c, b_c, g_d, b_d, xcur, abf, D);

    // ===== stage 3: FFN =====
    gemm256<1, true, false><<<gFFN, blk512, 0, stream>>>(abf, wf0, f0_b, nullptr, Qb, D, D, D, D, 1.f, 0, 0, 0, 0);
    gemm256<1, true, true><<<gFFN, blk512, 0, stream>>>(Qb, wf1, f1_b, tmp, nullptr, D, D, D, D, 1.f, 0, 0, 0, 0);
    ln_single<<<dim3(M), blk256, 0, stream>>>(tmp, xcur, g_d, b_d, dout, D);
}

// Round 4
// 549.220 us; speedup vs baseline: 1.1702x; 1.0057x over previous
//
#include <hip/hip_runtime.h>

#define DEV __device__ __forceinline__

typedef __attribute__((ext_vector_type(8))) short bf16x8;
typedef __attribute__((ext_vector_type(4))) float f32x4;

DEV float bf2f(unsigned short u) { return __uint_as_float(((unsigned int)u) << 16); }
DEV unsigned short f2bf(float f) {
    unsigned int x = __float_as_uint(f);
    return (unsigned short)((x + 0x7fffu + ((x >> 16) & 1u)) >> 16);
}
DEV float gelu_exact(float x) { return 0.5f * x * (1.0f + erff(x * 0.7071067811865475f)); }

DEV void gload16(const void* g, void* l) {
    __builtin_amdgcn_global_load_lds((const __attribute__((address_space(1))) void*)g,
                                     (__attribute__((address_space(3))) void*)l, 16, 0, 0);
}

// inline-asm LDS read: opaque to the compiler's LDS-DMA alias analysis, so it
// cannot insert per-phase s_waitcnt vmcnt(0) drains (the R3 killer).
template <int OFF>
DEV bf16x8 ds_read128(unsigned addr) {
    bf16x8 r;
    asm volatile("ds_read_b128 %0, %1 offset:%2" : "=v"(r) : "v"(addr), "i"(OFF));
    return r;
}

// ---------------------------------------------------------------------------
// transpose + cast: w f32 [R][C] -> wT bf16 [C][R]
__global__ __launch_bounds__(256) void transpose_cast_w(const float* __restrict__ in,
                                                        unsigned short* __restrict__ out,
                                                        int R, int C) {
    __shared__ float tile[32][33];
    int c0 = blockIdx.x * 32, r0 = blockIdx.y * 32;
    int tx = threadIdx.x, ty = threadIdx.y;  // 32 x 8
#pragma unroll
    for (int i = 0; i < 32; i += 8)
        tile[ty + i][tx] = in[(size_t)(r0 + ty + i) * C + (c0 + tx)];
    __syncthreads();
#pragma unroll
    for (int i = 0; i < 32; i += 8)
        out[(size_t)(c0 + ty + i) * R + (r0 + tx)] = f2bf(tile[tx][ty + i]);
}

// f32 -> bf16 cast, 4 elems/thread
__global__ __launch_bounds__(256) void cast_f32_bf16(const float* __restrict__ in,
                                                     unsigned short* __restrict__ out, int n4) {
    int i = blockIdx.x * 256 + threadIdx.x;
    if (i >= n4) return;
    float4 v = ((const float4*)in)[i];
    unsigned short o[4] = {f2bf(v.x), f2bf(v.y), f2bf(v.z), f2bf(v.w)};
    *(uint2*)(out + (size_t)i * 4) = *(uint2*)o;
}

// ---------------------------------------------------------------------------
// 256x256 8-phase bf16 GEMM (T2+T3+T4+T5), asm ds_read + manual waits.
//   C = act( scale * (A @ BT^T) + bias ),  A:[M][K] lda, BT:[N][K] ldb, bf16.
//   8 waves (2M x 4N), BK=64, 2 K-tiles/iter, 8 phases, 128 KiB LDS dbuf.
//   Swizzle: 16B-chunk XOR c' = (c&~7)|((c&7)^(row&7)) on global src + ds_read.
//   BIAS_MODE: 0 = none, 1 = per-column, 2 = per-row.

// k-slot-outer order: 8 independent accumulators between reuses
template <int Q>
DEV void mfma16(const bf16x8 (&a)[2][2], const bf16x8 (&b)[4][2], f32x4 (&acc)[8][4]) {
#pragma unroll
    for (int ks = 0; ks < 2; ++ks)
#pragma unroll
        for (int n = 0; n < 4; ++n) {
            acc[2 * Q][n]     = __builtin_amdgcn_mfma_f32_16x16x32_bf16(a[0][ks], b[n][ks], acc[2 * Q][n], 0, 0, 0);
            acc[2 * Q + 1][n] = __builtin_amdgcn_mfma_f32_16x16x32_bf16(a[1][ks], b[n][ks], acc[2 * Q + 1][n], 0, 0, 0);
        }
}

template <int BIAS_MODE, bool GELU_ACT, bool OUT_F32>
__global__ __launch_bounds__(512, 2) void gemm256(const unsigned short* __restrict__ A,
                                                  const unsigned short* __restrict__ BT,
                                                  const float* __restrict__ bias,
                                                  float* __restrict__ Cf,
                                                  unsigned short* __restrict__ Cb,
                                                  int N, int K, int lda, int ldb, float scale,
                                                  long sA, long sB, long sC, long sBias) {
    A += (long)blockIdx.z * sA;
    BT += (long)blockIdx.z * sB;
    if (BIAS_MODE) bias += (long)blockIdx.z * sBias;

    const int tid = threadIdx.x;
    const int lane = tid & 63;
    const int wave = tid >> 6;          // 0..7
    const int wm = wave >> 2;           // 0..1 : 128-row strip
    const int wn = wave & 3;            // 0..3 : 64-col strip
    const int llo = lane & 15, lhi = lane >> 4;
    const int bm = blockIdx.x * 256, bn = blockIdx.y * 256;
    const int brow = (wn & 1) * 64;

    __shared__ unsigned short lds[2][4][128 * 64];  // [buf][A0,A1,B0,B1] = 128 KiB

    // ds_read swizzled k-offsets
    const int xk0 = (0 + lhi) ^ (llo & 7);
    const int xk1 = (4 + lhi) ^ (llo & 7);

    // LDS byte addresses for asm ds_read (generic->LDS low-32 = LDS offset)
    const unsigned ldsA = (unsigned)(size_t)&lds[0][wm][0] + (unsigned)llo * 128u;
    const unsigned ldsB = (unsigned)(size_t)&lds[0][2 + (wn >> 1)][0] + (unsigned)(brow + llo) * 128u;
    unsigned aA[2][2], aB[2][2];
    aA[0][0] = ldsA + xk0 * 16; aA[0][1] = ldsA + xk1 * 16;
    aA[1][0] = aA[0][0] + 65536u; aA[1][1] = aA[0][1] + 65536u;
    aB[0][0] = ldsB + xk0 * 16; aB[0][1] = ldsB + xk1 * 16;
    aB[1][0] = aB[0][0] + 65536u; aB[1][1] = aB[0][1] + 65536u;

    // staging: thread covers 16B chunks d0 = wave*64+lane and d1 = d0+512 of a
    // [128][64] half; source chunk column XOR-swizzled, LDS dest linear.
    const int d0 = wave * 64 + lane;
    const int sr0 = d0 >> 3, sq0 = (d0 & 7) ^ (sr0 & 7);
    const int d1 = 512 + d0;
    const int sr1 = d1 >> 3, sq1 = (d1 & 7) ^ (sr1 & 7);

    const unsigned short* gA0 = A + (size_t)bm * lda;
    const unsigned short* gA1 = A + (size_t)(bm + 128) * lda;
    const unsigned short* gB0 = BT + (size_t)bn * ldb;
    const unsigned short* gB1 = BT + (size_t)(bn + 128) * ldb;

#define STAGE(grow, ld, kt, l)                                                          \
    {                                                                                   \
        gload16((grow) + (size_t)sr0 * (ld) + (kt) + sq0 * 8, (l) + wave * 512);        \
        gload16((grow) + (size_t)sr1 * (ld) + (kt) + sq1 * 8, (l) + 4096 + wave * 512); \
    }

    f32x4 acc[8][4] = {};
    bf16x8 b[4][2];

#define PH(Q, BUF, LOADB, STG, TAIL)                                         \
    {                                                                        \
        bf16x8 afr[2][2];                                                    \
        afr[0][0] = ds_read128<(Q)*4096>(aA[BUF][0]);                        \
        afr[0][1] = ds_read128<(Q)*4096>(aA[BUF][1]);                        \
        afr[1][0] = ds_read128<(Q)*4096 + 2048>(aA[BUF][0]);                 \
        afr[1][1] = ds_read128<(Q)*4096 + 2048>(aA[BUF][1]);                 \
        if (LOADB) {                                                         \
            b[0][0] = ds_read128<0>(aB[BUF][0]);                             \
            b[0][1] = ds_read128<0>(aB[BUF][1]);                             \
            b[1][0] = ds_read128<2048>(aB[BUF][0]);                          \
            b[1][1] = ds_read128<2048>(aB[BUF][1]);                          \
            b[2][0] = ds_read128<4096>(aB[BUF][0]);                          \
            b[2][1] = ds_read128<4096>(aB[BUF][1]);                          \
            b[3][0] = ds_read128<6144>(aB[BUF][0]);                          \
            b[3][1] = ds_read128<6144>(aB[BUF][1]);                          \
        }                                                                    \
        STG;                                                                 \
        __builtin_amdgcn_s_barrier();                                        \
        asm volatile("s_waitcnt lgkmcnt(0)" :::);                            \
        __builtin_amdgcn_sched_barrier(0); /* rule #18: pin MFMA below wait */\
        __builtin_amdgcn_s_setprio(1);                                       \
        mfma16<Q>(afr, b, acc);                                              \
        __builtin_amdgcn_s_setprio(0);                                       \
        TAIL;                                                                \
        __builtin_amdgcn_s_barrier();                                        \
    }

#define VM4 asm volatile("s_waitcnt vmcnt(4)" :::)
#define VM0 asm volatile("s_waitcnt vmcnt(0)" :::)
#define NOP ((void)0)

    const int nt = K >> 6;       // K-tiles of 64
    const int niter = nt >> 1;   // 2 K-tiles per iteration

    // prologue: buf0 <- tile0 (4 halves), buf1.B <- tile1 B halves
    STAGE(gA0, lda, 0, lds[0][0]);
    STAGE(gA1, lda, 0, lds[0][1]);
    STAGE(gB0, ldb, 0, lds[0][2]);
    STAGE(gB1, ldb, 0, lds[0][3]);
    STAGE(gB0, ldb, 64, lds[1][2]);
    STAGE(gB1, ldb, 64, lds[1][3]);
    VM4;
    __builtin_amdgcn_s_barrier();

    int kt = 0;
    for (int i = 0; i < niter - 1; ++i) {
        const int kt1 = kt + 64, kt2 = kt + 128, kt3 = kt + 192;
        PH(0, 0, true,  STAGE(gA0, lda, kt1, lds[1][0]), NOP);
        PH(1, 0, false, STAGE(gA1, lda, kt1, lds[1][1]), NOP);
        PH(2, 0, false, STAGE(gB0, ldb, kt2, lds[0][2]), NOP);
        PH(3, 0, false, STAGE(gB1, ldb, kt2, lds[0][3]), VM4);
        PH(0, 1, true,  STAGE(gA0, lda, kt2, lds[0][0]), NOP);
        PH(1, 1, false, STAGE(gA1, lda, kt2, lds[0][1]), NOP);
        PH(2, 1, false, STAGE(gB0, ldb, kt3, lds[1][2]), NOP);
        PH(3, 1, false, STAGE(gB1, ldb, kt3, lds[1][3]), VM4);
        kt += 128;
    }
    {
        const int kt1 = kt + 64;
        PH(0, 0, true,  STAGE(gA0, lda, kt1, lds[1][0]), NOP);
        PH(1, 0, false, STAGE(gA1, lda, kt1, lds[1][1]), NOP);
        PH(2, 0, false, NOP, NOP);
        PH(3, 0, false, NOP, VM0);
        PH(0, 1, true,  NOP, NOP);
        PH(1, 1, false, NOP, NOP);
        PH(2, 1, false, NOP, NOP);
        PH(3, 1, false, NOP, NOP);
    }
#undef PH
#undef STAGE
#undef VM4
#undef VM0
#undef NOP

    // epilogue: C/D frag layout col = llo, row = lhi*4 + j
#pragma unroll
    for (int m = 0; m < 8; ++m) {
#pragma unroll
        for (int n = 0; n < 4; ++n) {
            const int col = bn + wn * 64 + n * 16 + llo;
            float bcol = 0.f;
            if constexpr (BIAS_MODE == 1) bcol = bias[col];
#pragma unroll
            for (int j = 0; j < 4; ++j) {
                const int row = bm + wm * 128 + m * 16 + lhi * 4 + j;
                float v = acc[m][n][j] * scale + bcol;
                if constexpr (BIAS_MODE == 2) v += bias[row];
                if constexpr (GELU_ACT) v = gelu_exact(v);
                const size_t idx = (size_t)blockIdx.z * (size_t)sC + (size_t)row * N + col;
                if constexpr (OUT_F32) Cf[idx] = v;
                else Cb[idx] = f2bf(v);
            }
        }
    }
}

// ---------------------------------------------------------------------------
// row softmax in place on bf16 scores, one block per row, T = 8*blockDim.x
__global__ __launch_bounds__(256) void softmax_rows(unsigned short* __restrict__ s, int T) {
    __shared__ float red[4];
    unsigned short* p = s + (size_t)blockIdx.x * T;
    const int tid = threadIdx.x;

    uint4 raw = *(const uint4*)(p + tid * 8);
    const unsigned short* u = (const unsigned short*)&raw;
    float v[8];
#pragma unroll
    for (int j = 0; j < 8; ++j) v[j] = bf2f(u[j]);

    float mx = -3.4e38f;
#pragma unroll
    for (int j = 0; j < 8; ++j) mx = fmaxf(mx, v[j]);
#pragma unroll
    for (int o = 32; o; o >>= 1) mx = fmaxf(mx, __shfl_xor(mx, o));
    if ((tid & 63) == 0) red[tid >> 6] = mx;
    __syncthreads();
    mx = fmaxf(fmaxf(red[0], red[1]), fmaxf(red[2], red[3]));
    __syncthreads();

    float sum = 0.f;
#pragma unroll
    for (int j = 0; j < 8; ++j) {
        v[j] = expf(v[j] - mx);
        sum += v[j];
    }
#pragma unroll
    for (int o = 32; o; o >>= 1) sum += __shfl_xor(sum, o);
    if ((tid & 63) == 0) red[tid >> 6] = sum;
    __syncthreads();
    sum = red[0] + red[1] + red[2] + red[3];
    const float inv = 1.0f / sum;

    unsigned short o8[8];
#pragma unroll
    for (int j = 0; j < 8; ++j) o8[j] = f2bf(v[j] * inv);
    *(uint4*)(p + tid * 8) = *(uint4*)o8;
}

// ---------------------------------------------------------------------------
DEV float block_sum(float v, float* red, int tid) {
#pragma unroll
    for (int o = 32; o; o >>= 1) v += __shfl_xor(v, o);
    if ((tid & 63) == 0) red[tid >> 6] = v;
    __syncthreads();
    v = red[0] + red[1] + red[2] + red[3];
    __syncthreads();
    return v;
}

// x1 = LN2( LN1(av + x)*g1+b1 + x ); writes x1 (f32) and bf16(x1). D=1024, 4/thread.
__global__ __launch_bounds__(256) void ln_double(const float* __restrict__ av,
                                                 const float* __restrict__ xin,
                                                 const float* __restrict__ g1, const float* __restrict__ b1,
                                                 const float* __restrict__ g2, const float* __restrict__ b2,
                                                 float* __restrict__ xout,
                                                 unsigned short* __restrict__ xbf, int D) {
    __shared__ float red[4];
    const int tid = threadIdx.x;
    const size_t base = (size_t)blockIdx.x * D + tid * 4;
    const float4 a4 = *(const float4*)(av + base);
    const float4 x4 = *(const float4*)(xin + base);
    float x[4] = {x4.x, x4.y, x4.z, x4.w};
    float t[4] = {a4.x + x[0], a4.y + x[1], a4.z + x[2], a4.w + x[3]};
    const float invD = 1.0f / D;

    float m = block_sum(t[0] + t[1] + t[2] + t[3], red, tid) * invD;
    float q = 0.f;
#pragma unroll
    for (int j = 0; j < 4; ++j) q += (t[j] - m) * (t[j] - m);
    q = block_sum(q, red, tid) * invD;
    float rs = rsqrtf(q + 1e-5f);

    float u[4];
#pragma unroll
    for (int j = 0; j < 4; ++j) {
        const int idx = tid * 4 + j;
        u[j] = (t[j] - m) * rs * g1[idx] + b1[idx] + x[j];
    }
    float m2 = block_sum(u[0] + u[1] + u[2] + u[3], red, tid) * invD;
    float q2 = 0.f;
#pragma unroll
    for (int j = 0; j < 4; ++j) q2 += (u[j] - m2) * (u[j] - m2);
    q2 = block_sum(q2, red, tid) * invD;
    float rs2 = rsqrtf(q2 + 1e-5f);

    float4 o4;
    unsigned short ob[4];
#pragma unroll
    for (int j = 0; j < 4; ++j) {
        const int idx = tid * 4 + j;
        float o = (u[j] - m2) * rs2 * g2[idx] + b2[idx];
        ((float*)&o4)[j] = o;
        ob[j] = f2bf(o);
    }
    *(float4*)(xout + base) = o4;
    *(uint2*)(xbf + base) = *(uint2*)ob;
}

// out = LN(a + b)*g + bb  (final LN to d_out)
__global__ __launch_bounds__(256) void ln_single(const float* __restrict__ a,
                                                 const float* __restrict__ b_,
                                                 const float* __restrict__ g, const float* __restrict__ bb,
                                                 float* __restrict__ out, int D) {
    __shared__ float red[4];
    const int tid = threadIdx.x;
    const size_t base = (size_t)blockIdx.x * D + tid * 4;
    const float4 a4 = *(const float4*)(a + base);
    const float4 x4 = *(const float4*)(b_ + base);
    float t[4] = {a4.x + x4.x, a4.y + x4.y, a4.z + x4.z, a4.w + x4.w};
    const float invD = 1.0f / D;
    float m = block_sum(t[0] + t[1] + t[2] + t[3], red, tid) * invD;
    float q = 0.f;
#pragma unroll
    for (int j = 0; j < 4; ++j) q += (t[j] - m) * (t[j] - m);
    q = block_sum(q, red, tid) * invD;
    float rs = rsqrtf(q + 1e-5f);
    float4 o4;
#pragma unroll
    for (int j = 0; j < 4; ++j) {
        const int idx = tid * 4 + j;
        ((float*)&o4)[j] = (t[j] - m) * rs * g[idx] + bb[idx];
    }
    *(float4*)(out + base) = o4;
}

// ---------------------------------------------------------------------------
extern "C" void kernel_launch(void* const* d_in, const int* in_sizes, int n_in,
                              void* d_out, int out_size, void* d_ws, size_t ws_size,
                              hipStream_t stream) {
    (void)in_sizes; (void)n_in; (void)out_size; (void)ws_size;
    constexpr int B = 4, S = 2048, T = 2048, D = 1024;
    constexpr int M = B * S;  // 8192
    constexpr long MD = (long)M * D;
    constexpr long ST = (long)S * T;
    constexpr long DD = (long)D * D;

    const float* x = (const float*)d_in[0];
    const float* y = (const float*)d_in[1];
    const float* w_in[8] = {(const float*)d_in[2],  (const float*)d_in[4],  (const float*)d_in[6],
                            (const float*)d_in[10], (const float*)d_in[12], (const float*)d_in[14],
                            (const float*)d_in[18], (const float*)d_in[20]};
    const float* bq_m = (const float*)d_in[3];
    const float* bk_m = (const float*)d_in[5];
    const float* bv_m = (const float*)d_in[7];
    const float* g_m = (const float*)d_in[8];
    const float* b_m = (const float*)d_in[9];
    const float* bq_c = (const float*)d_in[11];
    const float* bk_c = (const float*)d_in[13];
    const float* bv_c = (const float*)d_in[15];
    const float* g_c = (const float*)d_in[16];
    const float* b_c = (const float*)d_in[17];
    const float* f0_b = (const float*)d_in[19];
    const float* f1_b = (const float*)d_in[21];
    const float* g_d = (const float*)d_in[22];
    const float* b_d = (const float*)d_in[23];
    float* dout = (float*)d_out;

    // workspace carve
    char* p = (char*)d_ws;
    auto carve = [&](size_t bytes) { void* r = p; p += (bytes + 255) & ~(size_t)255; return r; };
    float* xcur = (float*)carve(MD * 4);
    unsigned short* wT = (unsigned short*)carve((size_t)8 * DD * 2);
    unsigned short* abf = (unsigned short*)carve(MD * 2);   // abf, ybf adjacent (stride MD)
    unsigned short* ybf = (unsigned short*)carve(MD * 2);
    unsigned short* Qb = (unsigned short*)carve(MD * 2);    // Qb, Kb adjacent (stride MD)
    unsigned short* Kb = (unsigned short*)carve(MD * 2);
    unsigned short* Vt = (unsigned short*)carve(MD * 2);
    unsigned short* scores = (unsigned short*)carve((size_t)B * ST * 2);
    float* tmp = (float*)carve(MD * 4);
    float* bqk_m = (float*)carve(2 * D * 4);  // [bq_m ; bk_m]
    float* bqk_c = (float*)carve(2 * D * 4);  // [bq_c ; bk_c]

    const dim3 blk256(256), blk512(512);
    const dim3 tb(32, 8);

    // setup: weight transposes, input casts, adjacent bias staging
    for (int w = 0; w < 8; ++w)
        transpose_cast_w<<<dim3(32, 32), tb, 0, stream>>>(w_in[w], wT + (size_t)w * DD, D, D);
    cast_f32_bf16<<<dim3(M * D / 4 / 256), blk256, 0, stream>>>(x, abf, M * D / 4);
    cast_f32_bf16<<<dim3(M * D / 4 / 256), blk256, 0, stream>>>(y, ybf, M * D / 4);
    hipMemcpyAsync(bqk_m, bq_m, D * 4, hipMemcpyDeviceToDevice, stream);
    hipMemcpyAsync(bqk_m + D, bk_m, D * 4, hipMemcpyDeviceToDevice, stream);
    hipMemcpyAsync(bqk_c, bq_c, D * 4, hipMemcpyDeviceToDevice, stream);
    hipMemcpyAsync(bqk_c + D, bk_c, D * 4, hipMemcpyDeviceToDevice, stream);

    unsigned short* wqm = wT + 0 * DD;
    unsigned short* wvm = wT + 2 * DD;
    unsigned short* wqc = wT + 3 * DD;
    unsigned short* wvc = wT + 5 * DD;
    unsigned short* wf0 = wT + 6 * DD;
    unsigned short* wf1 = wT + 7 * DD;

    const dim3 gQK(M / 256, D / 256, 2);     // 32 x 4 x 2 = 256 blocks
    const dim3 gVt(D / 256, T / 256, B);     // 4 x 8 x 4  = 128 blocks
    const dim3 gScores(S / 256, T / 256, B); // 8 x 8 x 4  = 256 blocks
    const dim3 gPV(S / 256, D / 256, B);     // 8 x 4 x 4  = 128 blocks
    const dim3 gFFN(M / 256, D / 256, 1);    // 32 x 4     = 128 blocks

    // ===== stage 1: self attention =====
    gemm256<1, false, false><<<gQK, blk512, 0, stream>>>(abf, wqm, bqk_m, nullptr, Qb, D, D, D, D, 1.f, 0, DD, MD, D);
    gemm256<2, false, false><<<gVt, blk512, 0, stream>>>(wvm, abf, bv_m, nullptr, Vt, T, D, D, D, 1.f, 0, (long)S * D, (long)D * T, 0);
    gemm256<0, false, false><<<gScores, blk512, 0, stream>>>(Qb, Kb, nullptr, nullptr, scores, T, D, D, D, 0.125f, (long)S * D, (long)T * D, ST, 0);
    softmax_rows<<<dim3(B * S), blk256, 0, stream>>>(scores, T);
    gemm256<0, false, true><<<gPV, blk512, 0, stream>>>(scores, Vt, nullptr, tmp, nullptr, D, T, T, T, 1.f, ST, (long)T * D, (long)S * D, 0);
    ln_double<<<dim3(M), blk256, 0, stream>>>(tmp, x, g_m, b_m, g_d, b_d, xcur, abf, D);

    // ===== stage 2: cross attention =====
    gemm256<1, false, false><<<gQK, blk512, 0, stream>>>(abf, wqc, bqk_c, nullptr, Qb, D, D, D, D, 1.f, MD, DD, MD, D);
    gemm256<2, false, false><<<gVt, blk512, 0, stream>>>(wvc, ybf, bv_c, nullptr, Vt, T, D, D, D, 1.f, 0, (long)S * D, (long)D * T, 0);
    gemm256<0, false, false><<<gScores, blk512, 0, stream>>>(Qb, Kb, nullptr, nullptr, scores, T, D, D, D, 0.125f, (long)S * D, (long)T * D, ST, 0);
    softmax_rows<<<dim3(B * S), blk256, 0, stream>>>(scores, T);
    gemm256<0, false, true><<<gPV, blk512, 0, stream>>>(scores, Vt, nullptr, tmp, nullptr, D, T, T, T, 1.f, ST, (long)T * D, (long)S * D, 0);
    ln_double<<<dim3(M), blk256, 0, stream>>>(tmp, xcur, g_c, b_c, g_d, b_d, xcur, abf, D);

    // ===== stage 3: FFN =====
    gemm256<1, true, false><<<gFFN, blk512, 0, stream>>>(abf, wf0, f0_b, nullptr, Qb, D, D, D, D, 1.f, 0, 0, 0, 0);
    gemm256<1, true, true><<<gFFN, blk512, 0, stream>>>(Qb, wf1, f1_b, tmp, nullptr, D, D, D, D, 1.f, 0, 0, 0, 0);
    ln_single<<<dim3(M), blk256, 0, stream>>>(tmp, xcur, g_d, b_d, dout, D);
}